// Round 1
// baseline (495.126 us; speedup 1.0000x reference)
//
#include <hip/hip_runtime.h>

// Problem constants (from reference setup_inputs): B=8, C=128, H=W=256, K=7, pad=3
#define Bc 8
#define Cc 128
#define Hc 256
#define Wc 256
#define HWc (Hc * Wc)          // 65536
#define CHWc (Cc * HWc)        // 8388608

// ---------------------------------------------------------------------------
// K1: pooled[b,h,w] = max_c input[b,c,h,w]
// One thread per 4 consecutive w positions (float4). Loop over 128 channels
// with stride-HW float4 loads — coalesced across the wave each iteration.
// ---------------------------------------------------------------------------
__global__ void __launch_bounds__(256) channel_max_kernel(const float* __restrict__ in,
                                                          float* __restrict__ pooled) {
    int tid = blockIdx.x * blockDim.x + threadIdx.x;   // 0 .. B*HW/4-1
    int e = tid << 2;                                  // flat index into [B,HW]
    int b = e / HWc;
    int s = e - b * HWc;
    const float4* base = (const float4*)(in + (size_t)b * CHWc + s);
    const int cstride = HWc / 4;                       // float4 stride between channels
    float4 m = base[0];
#pragma unroll 4
    for (int c = 1; c < Cc; ++c) {
        float4 v = base[(size_t)c * cstride];
        m.x = fmaxf(m.x, v.x);
        m.y = fmaxf(m.y, v.y);
        m.z = fmaxf(m.z, v.z);
        m.w = fmaxf(m.w, v.w);
    }
    ((float4*)pooled)[tid] = m;
}

// ---------------------------------------------------------------------------
// K2: attn[b,h,w] = sigmoid( conv7x7(pooled, wgt, zero-pad 3) + bias )
// One thread per spatial pixel; pooled is 2 MiB -> L2-resident. Weights in LDS.
// ---------------------------------------------------------------------------
__global__ void __launch_bounds__(256) conv_sigmoid_kernel(const float* __restrict__ pooled,
                                                           const float* __restrict__ wgt,
                                                           const float* __restrict__ bias,
                                                           float* __restrict__ attn) {
    __shared__ float wsm[49];
    if (threadIdx.x < 49) wsm[threadIdx.x] = wgt[threadIdx.x];
    __syncthreads();

    int tid = blockIdx.x * blockDim.x + threadIdx.x;   // 0 .. B*HW-1
    int b = tid / HWc;
    int s = tid - b * HWc;
    int h = s >> 8;            // / Wc
    int w = s & (Wc - 1);      // % Wc
    const float* p = pooled + b * HWc;

    float acc = bias[0];
#pragma unroll
    for (int i = 0; i < 7; ++i) {
        int hh = h - 3 + i;
        if ((unsigned)hh < (unsigned)Hc) {
            const float* row = p + hh * Wc;
#pragma unroll
            for (int j = 0; j < 7; ++j) {
                int ww = w - 3 + j;
                if ((unsigned)ww < (unsigned)Wc) {
                    acc = fmaf(row[ww], wsm[i * 7 + j], acc);
                }
            }
        }
    }
    attn[tid] = 1.0f / (1.0f + expf(-acc));
}

// ---------------------------------------------------------------------------
// K3: out[b,c,h,w] = input[b,c,h,w] * attn[b,h,w]   (float4 streaming)
// ---------------------------------------------------------------------------
__global__ void __launch_bounds__(256) mul_kernel(const float* __restrict__ in,
                                                  const float* __restrict__ attn,
                                                  float* __restrict__ out) {
    unsigned tid = blockIdx.x * blockDim.x + threadIdx.x;   // 0 .. total/4-1
    unsigned e = tid << 2;                                  // flat elem index
    unsigned b = e / (unsigned)CHWc;
    unsigned s = e & (HWc - 1);                             // e % HW (HW is pow2)
    float4 v = *(const float4*)(in + e);
    float4 a = *(const float4*)(attn + b * HWc + s);
    v.x *= a.x;
    v.y *= a.y;
    v.z *= a.z;
    v.w *= a.w;
    *(float4*)(out + e) = v;
}

extern "C" void kernel_launch(void* const* d_in, const int* in_sizes, int n_in,
                              void* d_out, int out_size, void* d_ws, size_t ws_size,
                              hipStream_t stream) {
    const float* input  = (const float*)d_in[0];   // [8,128,256,256]
    const float* conv_w = (const float*)d_in[1];   // [1,1,7,7]
    const float* conv_b = (const float*)d_in[2];   // [1]
    float* out = (float*)d_out;

    // workspace layout: pooled [B*HW] then attn [B*HW]
    float* pooled = (float*)d_ws;
    float* attn   = pooled + (size_t)Bc * HWc;

    // K1: 8*65536/4 threads = 131072 -> 512 blocks of 256
    channel_max_kernel<<<(Bc * HWc / 4) / 256, 256, 0, stream>>>(input, pooled);

    // K2: 8*65536 threads -> 2048 blocks of 256
    conv_sigmoid_kernel<<<(Bc * HWc) / 256, 256, 0, stream>>>(pooled, conv_w, conv_b, attn);

    // K3: 67108864/4 threads -> 65536 blocks of 256
    mul_kernel<<<(Bc * CHWc / 4) / 256, 256, 0, stream>>>(input, attn, out);
}

// Round 3
// 487.646 us; speedup vs baseline: 1.0153x; 1.0153x over previous
//
#include <hip/hip_runtime.h>

// Problem constants: B=8, C=128, H=W=256, K=7, pad=3
#define Bc 8
#define Cc 128
#define Hc 256
#define Wc 256
#define HWc (Hc * Wc)          // 65536
#define CHWc (Cc * HWc)        // 8388608

typedef float floatx4 __attribute__((ext_vector_type(4)));  // native vec: OK for nontemporal builtins

// ---------------------------------------------------------------------------
// K1: pooled[b,h,w] = max_c input[b,c,h,w]
// One thread per 4 consecutive w positions (float4); loop 128 channels with
// stride-HW float4 loads (coalesced across the wave). Two independent max
// chains for ILP. Normal (caching) loads — we WANT input resident in L3
// for K3's re-read.
// ---------------------------------------------------------------------------
__global__ void __launch_bounds__(256) channel_max_kernel(const float* __restrict__ in,
                                                          float* __restrict__ pooled) {
    int tid = blockIdx.x * blockDim.x + threadIdx.x;   // 0 .. B*HW/4-1
    int e = tid << 2;                                  // flat index into [B,HW]
    int b = e / HWc;
    int s = e - b * HWc;
    const floatx4* base = (const floatx4*)(in + (size_t)b * CHWc + s);
    const int cstride = HWc / 4;                       // float4 stride between channels

    floatx4 m0 = base[0];
    floatx4 m1 = base[(size_t)cstride];
#pragma unroll 4
    for (int c = 2; c < Cc; c += 2) {
        floatx4 v0 = base[(size_t)c * cstride];
        floatx4 v1 = base[(size_t)(c + 1) * cstride];
        m0.x = fmaxf(m0.x, v0.x); m0.y = fmaxf(m0.y, v0.y);
        m0.z = fmaxf(m0.z, v0.z); m0.w = fmaxf(m0.w, v0.w);
        m1.x = fmaxf(m1.x, v1.x); m1.y = fmaxf(m1.y, v1.y);
        m1.z = fmaxf(m1.z, v1.z); m1.w = fmaxf(m1.w, v1.w);
    }
    floatx4 m;
    m.x = fmaxf(m0.x, m1.x); m.y = fmaxf(m0.y, m1.y);
    m.z = fmaxf(m0.z, m1.z); m.w = fmaxf(m0.w, m1.w);
    ((floatx4*)pooled)[tid] = m;
}

// ---------------------------------------------------------------------------
// K2: attn[b,h,w] = sigmoid( conv7x7(pooled, wgt, zero-pad 3) + bias )
// One thread per pixel; pooled (2 MiB) is L2-resident. Weights in LDS.
// ---------------------------------------------------------------------------
__global__ void __launch_bounds__(256) conv_sigmoid_kernel(const float* __restrict__ pooled,
                                                           const float* __restrict__ wgt,
                                                           const float* __restrict__ bias,
                                                           float* __restrict__ attn) {
    __shared__ float wsm[49];
    if (threadIdx.x < 49) wsm[threadIdx.x] = wgt[threadIdx.x];
    __syncthreads();

    int tid = blockIdx.x * blockDim.x + threadIdx.x;   // 0 .. B*HW-1
    int b = tid / HWc;
    int s = tid - b * HWc;
    int h = s >> 8;            // / Wc
    int w = s & (Wc - 1);      // % Wc
    const float* p = pooled + b * HWc;

    float acc = bias[0];
#pragma unroll
    for (int i = 0; i < 7; ++i) {
        int hh = h - 3 + i;
        if ((unsigned)hh < (unsigned)Hc) {
            const float* row = p + hh * Wc;
#pragma unroll
            for (int j = 0; j < 7; ++j) {
                int ww = w - 3 + j;
                if ((unsigned)ww < (unsigned)Wc) {
                    acc = fmaf(row[ww], wsm[i * 7 + j], acc);
                }
            }
        }
    }
    attn[tid] = 1.0f / (1.0f + expf(-acc));
}

// ---------------------------------------------------------------------------
// K3: out[b,c,h,w] = input[b,c,h,w] * attn[b,h,w]
// REVERSE block order: K1 just streamed the input through L3 (256 MiB =
// L3 capacity), so the tail is hottest — read it first. Output stores are
// nontemporal so the 256 MiB write-once stream doesn't evict cached input.
// ---------------------------------------------------------------------------
__global__ void __launch_bounds__(256) mul_kernel(const float* __restrict__ in,
                                                  const float* __restrict__ attn,
                                                  float* __restrict__ out) {
    unsigned rb = gridDim.x - 1u - blockIdx.x;              // reverse traversal
    unsigned tid = rb * blockDim.x + threadIdx.x;           // 0 .. total/4-1
    unsigned e = tid << 2;                                  // flat elem index
    unsigned b = e / (unsigned)CHWc;                        // pow2 -> shift
    unsigned s = e & (HWc - 1);                             // e % HW
    floatx4 v = *(const floatx4*)(in + e);
    floatx4 a = *(const floatx4*)(attn + b * HWc + s);
    v.x *= a.x;
    v.y *= a.y;
    v.z *= a.z;
    v.w *= a.w;
    __builtin_nontemporal_store(v, (floatx4*)(out + e));
}

extern "C" void kernel_launch(void* const* d_in, const int* in_sizes, int n_in,
                              void* d_out, int out_size, void* d_ws, size_t ws_size,
                              hipStream_t stream) {
    const float* input  = (const float*)d_in[0];   // [8,128,256,256]
    const float* conv_w = (const float*)d_in[1];   // [1,1,7,7]
    const float* conv_b = (const float*)d_in[2];   // [1]
    float* out = (float*)d_out;

    // workspace layout: pooled [B*HW] then attn [B*HW]
    float* pooled = (float*)d_ws;
    float* attn   = pooled + (size_t)Bc * HWc;

    // K1: 131072 threads -> 512 blocks of 256
    channel_max_kernel<<<(Bc * HWc / 4) / 256, 256, 0, stream>>>(input, pooled);

    // K2: 524288 threads -> 2048 blocks of 256
    conv_sigmoid_kernel<<<(Bc * HWc) / 256, 256, 0, stream>>>(pooled, conv_w, conv_b, attn);

    // K3: 16777216 threads -> 65536 blocks of 256
    mul_kernel<<<(Bc * CHWc / 4) / 256, 256, 0, stream>>>(input, attn, out);
}